// Round 7
// baseline (69.697 us; speedup 1.0000x reference)
//
#include <hip/hip_runtime.h>
#include <math.h>

// Problem constants
#define BATCH 4096
#define NFEAT 2048
#define NNEUR 1024
#define NTGT  8
#define NNZ1  65536
#define NNZ2  8192

// GEMM: h[m][n] = sigmoid( sum_k W1b[m][k] * xb[n][k] + b1[m] ), fused layer-2 partials
//   M = NNEUR (1024), N = BATCH (4096), K = NFEAT (2048)
// 128x64 tile, 256 threads (4 waves = 2m x 2n), grid 512 = 2 blocks/CU.
// Counted-vmcnt software pipeline (T3/T4): 4 LDS buffers, prefetch depth 3,
// ONE raw s_barrier per K-iter, vmcnt never drained to 0 in the main loop.
#define BM 128
#define BN 64
#define BK 32
#define KITERS (NFEAT / BK)

typedef short  bf16x8 __attribute__((ext_vector_type(8)));
typedef float  f32x4  __attribute__((ext_vector_type(4)));

// ---------------- workspace layout (bytes) ----------------
#define OFF_W1F  ((size_t)0)
#define OFF_W2D  ((size_t)8388608)
#define OFF_W1B  ((size_t)8421376)
#define OFF_XB   ((size_t)12615680)
#define OFF_PART ((size_t)29392896)

// W1f + W2d are contiguous: 8421376 B = 526336 float4
#define ZERO_FLOAT4 526336

__device__ __forceinline__ unsigned short f2bf(float f) {
    union { float f; unsigned int u; } a; a.f = f;
    unsigned int u = a.u;
    u += 0x7fffu + ((u >> 16) & 1u);   // round-to-nearest-even
    return (unsigned short)(u >> 16);
}

__device__ __forceinline__ void load_lds16(const unsigned short* g, unsigned short* l) {
    __builtin_amdgcn_global_load_lds(
        (const __attribute__((address_space(1))) unsigned int*)g,
        (__attribute__((address_space(3))) unsigned int*)l,
        16, 0, 0);
}

// fast zero of W1f+W2d
__global__ void k_zero4(float4* __restrict__ p) {
    int i = blockIdx.x * blockDim.x + threadIdx.x;
    p[i] = make_float4(0.f, 0.f, 0.f, 0.f);
}

// scatter-add edges into dense W1f and W2d (handles duplicate edges by summing)
__global__ void k_build(const float* __restrict__ w1, const int* __restrict__ c1o,
                        const int* __restrict__ c1i,
                        const float* __restrict__ w2, const int* __restrict__ c2o,
                        const int* __restrict__ c2i,
                        float* __restrict__ W1f, float* __restrict__ W2d) {
    int i = blockIdx.x * blockDim.x + threadIdx.x;
    if (i < NNZ1) {
        atomicAdd(&W1f[(size_t)c1o[i] * NFEAT + c1i[i]], w1[i]);
    } else {
        int j = i - NNZ1;
        if (j < NNZ2) atomicAdd(&W2d[c2i[j] * NTGT + c2o[j]], w2[j]);
    }
}

// convert W1f -> W1b and x -> xb, float4 -> 4x bf16 per thread
__global__ void k_convert(const float* __restrict__ W1f, const float* __restrict__ x,
                          unsigned short* __restrict__ W1b, unsigned short* __restrict__ xb) {
    int i = blockIdx.x * blockDim.x + threadIdx.x;
    const int nW = NNEUR * NFEAT / 4;
    const int nX = BATCH * NFEAT / 4;
    if (i < nW) {
        float4 v = ((const float4*)W1f)[i];
        ushort4 o;
        o.x = f2bf(v.x); o.y = f2bf(v.y); o.z = f2bf(v.z); o.w = f2bf(v.w);
        ((ushort4*)W1b)[i] = o;
    } else if (i < nW + nX) {
        int j = i - nW;
        float4 v = ((const float4*)x)[j];
        ushort4 o;
        o.x = f2bf(v.x); o.y = f2bf(v.y); o.z = f2bf(v.z); o.w = f2bf(v.w);
        ((ushort4*)xb)[j] = o;
    }
}

// bf16 MFMA GEMM with fused bias+sigmoid+layer2-partial epilogue.
__global__ __launch_bounds__(256) void k_gemm(const unsigned short* __restrict__ W1b,
                                              const unsigned short* __restrict__ xb,
                                              const float* __restrict__ b1,
                                              const float* __restrict__ W2d,
                                              float* __restrict__ partial) {
    __shared__ unsigned short ldsA[4][BM * BK];   // 4 x 8 KB
    __shared__ unsigned short ldsB[4][BN * BK];   // 4 x 4 KB
    __shared__ float s_w2[BM][NTGT];              // 4 KB
    __shared__ float s_b1[BM];                    // 512 B
    __shared__ float s_pt[2][BN][NTGT];           // 4 KB

    // bijective XCD swizzle
    int bid = blockIdx.x;                  // 0..511
    int v   = bid >> 3;                    // per-XCD index 0..63
    int n0  = ((bid & 7) * 8 + (v >> 3)) * BN;   // 64 n-tiles
    int mt  = v & 7;                       // 8 m-tiles
    int m0  = mt * BM;

    int tid  = threadIdx.x;
    int wv   = tid >> 6;
    int lane = tid & 63;
    int wm = wv >> 1, wn = wv & 1;         // wave grid 2m x 2n
    int lr = lane & 15, lg = lane >> 4;

    // preload W2d + b1 slices for the epilogue (read only after the main loop)
    for (int i = tid; i < BM * NTGT; i += 256)
        s_w2[i >> 3][i & 7] = W2d[(m0 + (i >> 3)) * NTGT + (i & 7)];
    if (tid < BM) s_b1[tid] = b1[m0 + tid];

    f32x4 zero4 = {0.f, 0.f, 0.f, 0.f};
    f32x4 acc[4][2];
#pragma unroll
    for (int i = 0; i < 4; ++i)
#pragma unroll
        for (int j = 0; j < 2; ++j) acc[i][j] = zero4;

    // staging (linear LDS dest, pre-swizzled global k-slot; rule #21).
    int uA1 = tid + 256;
    const unsigned short* gA0 = &W1b[(size_t)(m0 + (tid >> 2)) * NFEAT + ((tid & 3) ^ ((tid >> 3) & 3)) * 8];
    const unsigned short* gA1 = &W1b[(size_t)(m0 + (uA1 >> 2)) * NFEAT + ((uA1 & 3) ^ ((uA1 >> 3) & 3)) * 8];
    const unsigned short* gB  = &xb [(size_t)(n0 + (tid >> 2)) * NFEAT + ((tid & 3) ^ ((tid >> 3) & 3)) * 8];
    const int baseA0 = (wv * 64) * 8;
    const int baseA1 = (256 + wv * 64) * 8;
    const int baseB  = (wv * 64) * 8;

    // read-side swizzle: slot = lg ^ ((row>>1)&3)
    int swz = (lg ^ ((lr >> 1) & 3)) * 8;

#define STAGE(T, BUF) do { int k0 = (T) * BK;                      \
        load_lds16(gA0 + k0, &ldsA[BUF][baseA0]);                  \
        load_lds16(gA1 + k0, &ldsA[BUF][baseA1]);                  \
        load_lds16(gB  + k0, &ldsB[BUF][baseB]); } while (0)

#define COMPUTE(BUF) do {                                          \
        const unsigned short* bA = ldsA[BUF];                      \
        const unsigned short* bB = ldsB[BUF];                      \
        bf16x8 af[4], bg[2];                                       \
        _Pragma("unroll")                                          \
        for (int i = 0; i < 4; ++i)                                \
            af[i] = *(const bf16x8*)&bA[(wm * 64 + i * 16 + lr) * BK + swz]; \
        _Pragma("unroll")                                          \
        for (int j = 0; j < 2; ++j)                                \
            bg[j] = *(const bf16x8*)&bB[(wn * 32 + j * 16 + lr) * BK + swz]; \
        _Pragma("unroll")                                          \
        for (int i = 0; i < 4; ++i)                                \
            _Pragma("unroll")                                      \
            for (int j = 0; j < 2; ++j)                            \
                acc[i][j] = __builtin_amdgcn_mfma_f32_16x16x32_bf16(af[i], bg[j], acc[i][j], 0, 0, 0); \
    } while (0)

    // prologue: stage tiles 0,1,2 (9 loads in flight; plus the few preload loads above)
    STAGE(0, 0);
    STAGE(1, 1);
    STAGE(2, 2);

    // main loop: t = 0 .. KITERS-3. Per iter: wait own tile-t loads (leave 6 in
    // flight), barrier (=> ALL waves' tile-t stores visible; all waves finished
    // reading buf[(t-1)%4] since their ds_reads drained before their t-1 MFMA),
    // then stage t+3 into buf[(t+3)%4] == buf[(t-1)%4], then compute tile t.
    for (int t = 0; t < KITERS - 2; ++t) {
        asm volatile("s_waitcnt vmcnt(6)" ::: "memory");
        __builtin_amdgcn_s_barrier();
        if (t + 3 < KITERS) STAGE(t + 3, (t + 3) & 3);
        COMPUTE(t & 3);
    }
    // peeled tail: tiles KITERS-2 and KITERS-1
    asm volatile("s_waitcnt vmcnt(3)" ::: "memory");
    __builtin_amdgcn_s_barrier();
    COMPUTE((KITERS - 2) & 3);
    asm volatile("s_waitcnt vmcnt(0)" ::: "memory");
    __builtin_amdgcn_s_barrier();
    COMPUTE((KITERS - 1) & 3);

#undef STAGE
#undef COMPUTE

    // ---- fused epilogue: h = sigmoid(acc + b1); pt[j][t] = sum_m h * W2d[m][t] ----
    // C/D layout: col(n) = lane&15, row(m) = (lane>>4)*4 + reg   [m89-verified]
    float pt[2][NTGT];
#pragma unroll
    for (int j = 0; j < 2; ++j)
#pragma unroll
        for (int t = 0; t < NTGT; ++t) pt[j][t] = 0.f;

#pragma unroll
    for (int i = 0; i < 4; ++i) {
#pragma unroll
        for (int r = 0; r < 4; ++r) {
            int ml = wm * 64 + i * 16 + lg * 4 + r;
            float bn = s_b1[ml];
#pragma unroll
            for (int j = 0; j < 2; ++j) {
                float h = 1.f / (1.f + __expf(-(acc[i][j][r] + bn)));
#pragma unroll
                for (int t = 0; t < NTGT; ++t)
                    pt[j][t] += h * s_w2[ml][t];
            }
        }
    }
    // reduce over lg (lanes lr+16*lg share the same n column)
#pragma unroll
    for (int j = 0; j < 2; ++j)
#pragma unroll
        for (int t = 0; t < NTGT; ++t) {
            float val = pt[j][t];
            val += __shfl_xor(val, 16, 64);
            val += __shfl_xor(val, 32, 64);
            pt[j][t] = val;
        }
    if (lg == 0) {
#pragma unroll
        for (int j = 0; j < 2; ++j) {
            int nl = wn * 32 + j * 16 + lr;
#pragma unroll
            for (int t = 0; t < NTGT; ++t)
                s_pt[wm][nl][t] = pt[j][t];
        }
    }
    __syncthreads();
    // partial[mt][n][t], 64 n x 8 t per block
    for (int idx = tid; idx < BN * NTGT; idx += 256) {
        int nl = idx >> 3, t = idx & 7;
        partial[((size_t)mt * BATCH + (n0 + nl)) * NTGT + t] = s_pt[0][nl][t] + s_pt[1][nl][t];
    }
}

// out[b][t] = b2[t] + sum_mt partial[mt][b][t]
__global__ void k_reduce(const float* __restrict__ partial, const float* __restrict__ b2,
                         float* __restrict__ out) {
    int i = blockIdx.x * blockDim.x + threadIdx.x;  // 32768
    float v = b2[i & 7];
#pragma unroll
    for (int c = 0; c < 8; ++c) v += partial[(size_t)c * BATCH * NTGT + i];
    out[i] = v;
}

extern "C" void kernel_launch(void* const* d_in, const int* in_sizes, int n_in,
                              void* d_out, int out_size, void* d_ws, size_t ws_size,
                              hipStream_t stream) {
    (void)in_sizes; (void)n_in; (void)out_size; (void)ws_size;
    const float* x   = (const float*)d_in[0];
    const float* w1  = (const float*)d_in[1];
    const float* b1  = (const float*)d_in[2];
    const float* w2  = (const float*)d_in[3];
    const float* b2  = (const float*)d_in[4];
    const int*   c1o = (const int*)d_in[5];
    const int*   c1i = (const int*)d_in[6];
    const int*   c2o = (const int*)d_in[7];
    const int*   c2i = (const int*)d_in[8];
    float* out = (float*)d_out;

    char* ws = (char*)d_ws;
    float*          W1f  = (float*)(ws + OFF_W1F);
    float*          W2d  = (float*)(ws + OFF_W2D);
    unsigned short* W1b  = (unsigned short*)(ws + OFF_W1B);
    unsigned short* xb   = (unsigned short*)(ws + OFF_XB);
    float*          part = (float*)(ws + OFF_PART);

    // zero W1f + W2d with a custom vectorized kernel
    k_zero4<<<ZERO_FLOAT4 / 256, 256, 0, stream>>>((float4*)ws);

    // dense weight build
    k_build<<<(NNZ1 + NNZ2) / 256, 256, 0, stream>>>(w1, c1o, c1i, w2, c2o, c2i, W1f, W2d);

    // fp32 -> bf16 for MFMA operands
    k_convert<<<(NNEUR * NFEAT / 4 + BATCH * NFEAT / 4) / 256, 256, 0, stream>>>(W1f, x, W1b, xb);

    // layer 1 GEMM + bias + sigmoid + layer-2 partials, all fused
    k_gemm<<<(NNEUR / BM) * (BATCH / BN), 256, 0, stream>>>(W1b, xb, b1, W2d, part);

    // final reduce over the 8 m-tiles
    k_reduce<<<BATCH * NTGT / 256, 256, 0, stream>>>(part, b2, out);
}

// Round 8
// 65.306 us; speedup vs baseline: 1.0672x; 1.0672x over previous
//
#include <hip/hip_runtime.h>
#include <math.h>

// Problem constants
#define BATCH 4096
#define NFEAT 2048
#define NNEUR 1024
#define NTGT  8
#define NNZ1  65536
#define NNZ2  8192

// GEMM: h[m][n] = sigmoid( sum_k W1b[m][k] * xb[n][k] + b1[m] ), fused layer-2
// epilogue (atomicAdd into out). M=1024, N=4096, K=2048.
// 64x64 tile, 256 threads (4 waves = 2m x 2n), wave tile 32x32 -> 4096 waves
// = 4 waves/SIMD (2x Round-7). Grid 1024 = 4 blocks/CU (LDS 38.3KB).
// Depth-3 counted-vmcnt pipeline: 4 LDS buffers, vmcnt(4) in main loop.
#define BM 64
#define BN 64
#define BK 32
#define KITERS (NFEAT / BK)

typedef short  bf16x8 __attribute__((ext_vector_type(8)));
typedef float  f32x4  __attribute__((ext_vector_type(4)));

// ---------------- workspace layout (bytes) ----------------
#define OFF_W1F  ((size_t)0)
#define OFF_W2D  ((size_t)8388608)
#define OFF_W1B  ((size_t)8421376)
#define OFF_XB   ((size_t)12615680)

// W1f + W2d are contiguous: 8421376 B = 526336 float4
#define ZERO_FLOAT4 526336
#define OUT_FLOAT4  (BATCH * NTGT / 4)   // 8192

__device__ __forceinline__ unsigned short f2bf(float f) {
    union { float f; unsigned int u; } a; a.f = f;
    unsigned int u = a.u;
    u += 0x7fffu + ((u >> 16) & 1u);   // round-to-nearest-even
    return (unsigned short)(u >> 16);
}

__device__ __forceinline__ void load_lds16(const unsigned short* g, unsigned short* l) {
    __builtin_amdgcn_global_load_lds(
        (const __attribute__((address_space(1))) unsigned int*)g,
        (__attribute__((address_space(3))) unsigned int*)l,
        16, 0, 0);
}

// zero W1f+W2d and pre-fill out with b2 (out is then atomicAdd'ed by k_gemm)
__global__ void k_zero(float4* __restrict__ ws4, float4* __restrict__ out4,
                       const float* __restrict__ b2) {
    int i = blockIdx.x * blockDim.x + threadIdx.x;
    if (i < ZERO_FLOAT4) {
        ws4[i] = make_float4(0.f, 0.f, 0.f, 0.f);
    } else {
        int j = i - ZERO_FLOAT4;
        if (j < OUT_FLOAT4) {
            int p = (j & 1) * 4;
            out4[j] = make_float4(b2[p], b2[p + 1], b2[p + 2], b2[p + 3]);
        }
    }
}

// scatter-add edges into dense W1f and W2d (handles duplicate edges by summing)
__global__ void k_build(const float* __restrict__ w1, const int* __restrict__ c1o,
                        const int* __restrict__ c1i,
                        const float* __restrict__ w2, const int* __restrict__ c2o,
                        const int* __restrict__ c2i,
                        float* __restrict__ W1f, float* __restrict__ W2d) {
    int i = blockIdx.x * blockDim.x + threadIdx.x;
    if (i < NNZ1) {
        atomicAdd(&W1f[(size_t)c1o[i] * NFEAT + c1i[i]], w1[i]);
    } else {
        int j = i - NNZ1;
        if (j < NNZ2) atomicAdd(&W2d[c2i[j] * NTGT + c2o[j]], w2[j]);
    }
}

// convert W1f -> W1b and x -> xb, float4 -> 4x bf16 per thread
__global__ void k_convert(const float* __restrict__ W1f, const float* __restrict__ x,
                          unsigned short* __restrict__ W1b, unsigned short* __restrict__ xb) {
    int i = blockIdx.x * blockDim.x + threadIdx.x;
    const int nW = NNEUR * NFEAT / 4;
    const int nX = BATCH * NFEAT / 4;
    if (i < nW) {
        float4 v = ((const float4*)W1f)[i];
        ushort4 o;
        o.x = f2bf(v.x); o.y = f2bf(v.y); o.z = f2bf(v.z); o.w = f2bf(v.w);
        ((ushort4*)W1b)[i] = o;
    } else if (i < nW + nX) {
        int j = i - nW;
        float4 v = ((const float4*)x)[j];
        ushort4 o;
        o.x = f2bf(v.x); o.y = f2bf(v.y); o.z = f2bf(v.z); o.w = f2bf(v.w);
        ((ushort4*)xb)[j] = o;
    }
}

// bf16 MFMA GEMM with fused bias+sigmoid+layer2 epilogue (atomic into out).
__global__ __launch_bounds__(256) void k_gemm(const unsigned short* __restrict__ W1b,
                                              const unsigned short* __restrict__ xb,
                                              const float* __restrict__ b1,
                                              const float* __restrict__ W2d,
                                              float* __restrict__ out) {
    __shared__ unsigned short ldsA[4][BM * BK];   // 4 x 4 KB
    __shared__ unsigned short ldsB[4][BN * BK];   // 4 x 4 KB
    __shared__ float s_w2[BM][NTGT];              // 2 KB
    __shared__ float s_b1[BM];                    // 256 B
    __shared__ float s_pt[2][BN][NTGT];           // 4 KB

    // bijective XCD swizzle: xcd = bid&7 gets 8 contiguous n-tiles, m fastest
    int bid = blockIdx.x;                  // 0..1023
    int v   = bid >> 3;                    // 0..127
    int n0  = ((bid & 7) * 8 + (v >> 4)) * BN;   // 64 n-tiles
    int mt  = v & 15;                      // 16 m-tiles
    int m0  = mt * BM;

    int tid  = threadIdx.x;
    int wv   = tid >> 6;
    int lane = tid & 63;
    int wm = wv >> 1, wn = wv & 1;         // wave grid 2m x 2n, wave tile 32x32
    int lr = lane & 15, lg = lane >> 4;

    // preload W2d + b1 slices for the epilogue
    for (int i = tid; i < BM * NTGT; i += 256)
        s_w2[i >> 3][i & 7] = W2d[(m0 + (i >> 3)) * NTGT + (i & 7)];
    if (tid < BM) s_b1[tid] = b1[m0 + tid];
    // drain preloads so loop vmcnt counts only stage loads
    asm volatile("s_waitcnt vmcnt(0)" ::: "memory");

    f32x4 zero4 = {0.f, 0.f, 0.f, 0.f};
    f32x4 acc[2][2];
#pragma unroll
    for (int i = 0; i < 2; ++i)
#pragma unroll
        for (int j = 0; j < 2; ++j) acc[i][j] = zero4;

    // staging (linear LDS dest, pre-swizzled global k-slot; rule #21).
    // Tile 64x32 bf16 = 256 16B-units; unit u: row=u>>2, gslot=(u&3)^((row>>1)&3).
    // One load_lds16 call per operand covers the tile (256 threads).
    const unsigned short* gA = &W1b[(size_t)(m0 + (tid >> 2)) * NFEAT + ((tid & 3) ^ ((tid >> 3) & 3)) * 8];
    const unsigned short* gB = &xb [(size_t)(n0 + (tid >> 2)) * NFEAT + ((tid & 3) ^ ((tid >> 3) & 3)) * 8];
    const int base = (wv * 64) * 8;        // wave-uniform; lane lands at +lane*16B

    // read-side swizzle: slot = lg ^ ((row>>1)&3); row bases are 0 mod 16
    int swz = (lg ^ ((lr >> 1) & 3)) * 8;

#define STAGE(T, BUF) do { int k0 = (T) * BK;                      \
        load_lds16(gA + k0, &ldsA[BUF][base]);                     \
        load_lds16(gB + k0, &ldsB[BUF][base]); } while (0)

#define COMPUTE(BUF) do {                                          \
        const unsigned short* bA = ldsA[BUF];                      \
        const unsigned short* bB = ldsB[BUF];                      \
        bf16x8 af[2], bg[2];                                       \
        _Pragma("unroll")                                          \
        for (int i = 0; i < 2; ++i)                                \
            af[i] = *(const bf16x8*)&bA[(wm * 32 + i * 16 + lr) * BK + swz]; \
        _Pragma("unroll")                                          \
        for (int j = 0; j < 2; ++j)                                \
            bg[j] = *(const bf16x8*)&bB[(wn * 32 + j * 16 + lr) * BK + swz]; \
        _Pragma("unroll")                                          \
        for (int i = 0; i < 2; ++i)                                \
            _Pragma("unroll")                                      \
            for (int j = 0; j < 2; ++j)                            \
                acc[i][j] = __builtin_amdgcn_mfma_f32_16x16x32_bf16(af[i], bg[j], acc[i][j], 0, 0, 0); \
    } while (0)

    // prologue: stage tiles 0,1,2 (6 loads in flight per wave)
    STAGE(0, 0);
    STAGE(1, 1);
    STAGE(2, 2);

    // main loop: wait own tile-t loads (leave 4 in flight), barrier (all waves'
    // tile-t stores visible; buf[(t+3)&3]=buf[(t-1)&3] was fully read at t-1),
    // stage t+3, compute t.
    for (int t = 0; t <= KITERS - 4; ++t) {
        asm volatile("s_waitcnt vmcnt(4)" ::: "memory");
        __builtin_amdgcn_s_barrier();
        STAGE(t + 3, (t + 3) & 3);
        COMPUTE(t & 3);
    }
    // peeled tail: tiles KITERS-3, KITERS-2, KITERS-1
    asm volatile("s_waitcnt vmcnt(4)" ::: "memory");
    __builtin_amdgcn_s_barrier();
    COMPUTE((KITERS - 3) & 3);
    asm volatile("s_waitcnt vmcnt(2)" ::: "memory");
    __builtin_amdgcn_s_barrier();
    COMPUTE((KITERS - 2) & 3);
    asm volatile("s_waitcnt vmcnt(0)" ::: "memory");
    __builtin_amdgcn_s_barrier();
    COMPUTE((KITERS - 1) & 3);

#undef STAGE
#undef COMPUTE

    // ---- fused epilogue: h = sigmoid(acc + b1); pt[j][t] = sum_m h * W2d[m][t] ----
    // C/D layout: col(n) = lane&15, row(m) = (lane>>4)*4 + reg   [m89-verified]
    float pt[2][NTGT];
#pragma unroll
    for (int j = 0; j < 2; ++j)
#pragma unroll
        for (int t = 0; t < NTGT; ++t) pt[j][t] = 0.f;

#pragma unroll
    for (int i = 0; i < 2; ++i) {
#pragma unroll
        for (int r = 0; r < 4; ++r) {
            int ml = wm * 32 + i * 16 + lg * 4 + r;
            float bn = s_b1[ml];
#pragma unroll
            for (int j = 0; j < 2; ++j) {
                float h = 1.f / (1.f + __expf(-(acc[i][j][r] + bn)));
#pragma unroll
                for (int t = 0; t < NTGT; ++t)
                    pt[j][t] += h * s_w2[ml][t];
            }
        }
    }
    // reduce over lg (lanes lr+16*lg share the same n column)
#pragma unroll
    for (int j = 0; j < 2; ++j)
#pragma unroll
        for (int t = 0; t < NTGT; ++t) {
            float val = pt[j][t];
            val += __shfl_xor(val, 16, 64);
            val += __shfl_xor(val, 32, 64);
            pt[j][t] = val;
        }
    if (lg == 0) {
#pragma unroll
        for (int j = 0; j < 2; ++j) {
            int nl = wn * 32 + j * 16 + lr;
#pragma unroll
            for (int t = 0; t < NTGT; ++t)
                s_pt[wm][nl][t] = pt[j][t];
        }
    }
    __syncthreads();
    // atomic add 64 n x 8 t into out (pre-filled with b2); coalesced by tid
    for (int idx = tid; idx < BN * NTGT; idx += 256) {
        int nl = idx >> 3, t = idx & 7;
        atomicAdd(&out[(size_t)(n0 + nl) * NTGT + t], s_pt[0][nl][t] + s_pt[1][nl][t]);
    }
}

extern "C" void kernel_launch(void* const* d_in, const int* in_sizes, int n_in,
                              void* d_out, int out_size, void* d_ws, size_t ws_size,
                              hipStream_t stream) {
    (void)in_sizes; (void)n_in; (void)out_size; (void)ws_size;
    const float* x   = (const float*)d_in[0];
    const float* w1  = (const float*)d_in[1];
    const float* b1  = (const float*)d_in[2];
    const float* w2  = (const float*)d_in[3];
    const float* b2  = (const float*)d_in[4];
    const int*   c1o = (const int*)d_in[5];
    const int*   c1i = (const int*)d_in[6];
    const int*   c2o = (const int*)d_in[7];
    const int*   c2i = (const int*)d_in[8];
    float* out = (float*)d_out;

    char* ws = (char*)d_ws;
    float*          W1f  = (float*)(ws + OFF_W1F);
    float*          W2d  = (float*)(ws + OFF_W2D);
    unsigned short* W1b  = (unsigned short*)(ws + OFF_W1B);
    unsigned short* xb   = (unsigned short*)(ws + OFF_XB);

    // zero W1f+W2d, pre-fill out with b2
    k_zero<<<(ZERO_FLOAT4 + OUT_FLOAT4 + 255) / 256, 256, 0, stream>>>(
        (float4*)ws, (float4*)out, b2);

    // dense weight build
    k_build<<<(NNZ1 + NNZ2) / 256, 256, 0, stream>>>(w1, c1o, c1i, w2, c2o, c2i, W1f, W2d);

    // fp32 -> bf16 for MFMA operands
    k_convert<<<(NNEUR * NFEAT / 4 + BATCH * NFEAT / 4) / 256, 256, 0, stream>>>(W1f, x, W1b, xb);

    // layer 1 GEMM + bias + sigmoid + layer-2 (atomic) all fused
    k_gemm<<<(NNEUR / BM) * (BATCH / BN), 256, 0, stream>>>(W1b, xb, b1, W2d, out);
}